// Round 2
// baseline (2458.741 us; speedup 1.0000x reference)
//
#include <hip/hip_runtime.h>
#include <cmath>

// Problem constants (from reference: B,T,D,L,H = 64,1002,8,2,64)
namespace {
constexpr int BB   = 64;
constexpr int TT   = 1002;
constexpr int DD   = 8;
constexpr int HH   = 64;
constexpr int LAGS = 2;
constexpr int NW   = TT - LAGS;        // 1000 windows per batch row
constexpr int FIN  = LAGS * DD + 1;    // 17
constexpr int NTOT = BB * NW;          // 64000
constexpr int TILE = 256;              // threads per block = windows per block
constexpr int GX   = (NW + TILE - 1) / TILE;   // 4 blocks along w

// output layout (concatenated flat, return order)
constexpr int RES_OFF = 0;                 // residuals: (B, NW, D) = 512000
constexpr int LOG_OFF = NTOT * DD;         // sum_log_abs_det: (B,) = 64
constexpr int HJ_OFF  = LOG_OFF + BB;      // hist_jac: (D, NTOT, 1, 16) = 8192000
}

// amdgpu_waves_per_eu(2): min 2 waves/SIMD -> register budget 256 VGPRs/wave.
// Round-1 evidence: default allocation capped at 128 VGPRs and spilled the
// ~150-float live set (1.1 GB scratch traffic = the entire runtime).
__global__ __launch_bounds__(TILE)
__attribute__((amdgpu_waves_per_eu(2)))
void fused_mlp(
    const float* __restrict__ x,
    const float* __restrict__ W0, const float* __restrict__ b0, const float* __restrict__ a0,
    const float* __restrict__ W1, const float* __restrict__ b1, const float* __restrict__ a1,
    const float* __restrict__ W2, const float* __restrict__ b2, const float* __restrict__ a2,
    const float* __restrict__ W3, const float* __restrict__ b3,
    float* __restrict__ out, float* __restrict__ partials)
{
    const int bx  = blockIdx.x;   // 0..GX-1
    const int b   = blockIdx.y;   // 0..BB-1
    const int d   = blockIdx.z;   // 0..DD-1
    const int tid = threadIdx.x;
    const int w0  = bx * TILE;

    // Stage x[b, w0 .. w0+TILE+1, :] into LDS (contiguous copy)
    __shared__ float xs[(TILE + LAGS) * DD];
    {
        const int nload = min(TILE + LAGS, TT - w0) * DD;
        const float* src = x + (b * TT + w0) * DD;
        for (int i = tid; i < nload; i += TILE) xs[i] = src[i];
    }
    __syncthreads();

    const int  w     = w0 + tid;
    const bool valid = (w < NW);
    const int  wl    = valid ? tid : 0;   // clamped local window index

    // Build the 17-wide input: [x[b,w,:], x[b,w+1,:], x[b,w+2,d]]
    float inp[FIN];
    #pragma unroll
    for (int f = 0; f < 2 * DD; ++f) inp[f] = xs[wl * DD + f];
    inp[2 * DD] = xs[(wl + LAGS) * DD + d];

    const float A0 = a0[d], A1 = a1[d], A2 = a2[d];

    // ---- layer 0: z0[h] = b0[h] + sum_f inp[f]*W0[d,h,f]; PReLU ----
    float h0v[HH];
    unsigned long long m0 = 0ull;
    {
        const float* Wp = W0 + (size_t)d * HH * FIN;
        const float* bp = b0 + d * HH;
        #pragma unroll
        for (int h = 0; h < HH; ++h) {
            float z = bp[h];
            #pragma unroll
            for (int f = 0; f < FIN; ++f) z = fmaf(inp[f], Wp[h * FIN + f], z);
            const bool pos = z > 0.0f;
            m0 |= (unsigned long long)pos << h;
            h0v[h] = pos ? z : A0 * z;
        }
    }

    // ---- layer 1: z1[g] = b1[g] + sum_h h0[h]*W1[d,g,h]; PReLU ----
    float h1v[HH];
    unsigned long long m1 = 0ull;
    {
        const float* Wp = W1 + (size_t)d * HH * HH;
        const float* bp = b1 + d * HH;
        #pragma unroll
        for (int g = 0; g < HH; ++g) {
            float z = bp[g];
            const float* row = Wp + g * HH;
            #pragma unroll
            for (int h = 0; h < HH; ++h) z = fmaf(h0v[h], row[h], z);
            const bool pos = z > 0.0f;
            m1 |= (unsigned long long)pos << g;
            h1v[g] = pos ? z : A1 * z;
        }
    }

    // ---- layer 2: z2[g] = b2[g] + sum_h h1[h]*W2[d,g,h]; PReLU ----
    float h2v[HH];
    unsigned long long m2 = 0ull;
    {
        const float* Wp = W2 + (size_t)d * HH * HH;
        const float* bp = b2 + d * HH;
        #pragma unroll
        for (int g = 0; g < HH; ++g) {
            float z = bp[g];
            const float* row = Wp + g * HH;
            #pragma unroll
            for (int h = 0; h < HH; ++h) z = fmaf(h1v[h], row[h], z);
            const bool pos = z > 0.0f;
            m2 |= (unsigned long long)pos << g;
            h2v[g] = pos ? z : A2 * z;
        }
    }

    // ---- output: out = sum_h h2[h]*W3[d,0,h] + b3[d] ----
    float ov;
    {
        const float* Wp = W3 + d * HH;
        float z = b3[d];
        #pragma unroll
        for (int h = 0; h < HH; ++h) z = fmaf(h2v[h], Wp[h], z);
        ov = z;
    }

    // ---- backward VJP ----
    // v[h] = W3[d,0,h] * d2[h]
    float v[HH];
    {
        const float* Wp = W3 + d * HH;
        #pragma unroll
        for (int h = 0; h < HH; ++h)
            v[h] = Wp[h] * (((m2 >> h) & 1ull) ? 1.0f : A2);
    }
    // v = (v @ W2[d]) * d1   -> vn[h] = (sum_g v[g]*W2[d,g,h]) * d1[h]
    float vn[HH];
    {
        const float* Wp = W2 + (size_t)d * HH * HH;
        #pragma unroll
        for (int h = 0; h < HH; ++h) vn[h] = 0.0f;
        #pragma unroll
        for (int g = 0; g < HH; ++g) {
            const float* row = Wp + g * HH;
            const float vg = v[g];
            #pragma unroll
            for (int h = 0; h < HH; ++h) vn[h] = fmaf(vg, row[h], vn[h]);
        }
        #pragma unroll
        for (int h = 0; h < HH; ++h)
            vn[h] *= (((m1 >> h) & 1ull) ? 1.0f : A1);
    }
    // v = (vn @ W1[d]) * d0
    {
        const float* Wp = W1 + (size_t)d * HH * HH;
        #pragma unroll
        for (int h = 0; h < HH; ++h) v[h] = 0.0f;
        #pragma unroll
        for (int g = 0; g < HH; ++g) {
            const float* row = Wp + g * HH;
            const float vg = vn[g];
            #pragma unroll
            for (int h = 0; h < HH; ++h) v[h] = fmaf(vg, row[h], v[h]);
        }
        #pragma unroll
        for (int h = 0; h < HH; ++h)
            v[h] *= (((m0 >> h) & 1ull) ? 1.0f : A0);
    }
    // g[f] = sum_h v[h] * W0[d,h,f]
    float gf[FIN];
    {
        const float* Wp = W0 + (size_t)d * HH * FIN;
        #pragma unroll
        for (int f = 0; f < FIN; ++f) gf[f] = 0.0f;
        #pragma unroll
        for (int h = 0; h < HH; ++h) {
            const float* row = Wp + h * FIN;
            const float vh = v[h];
            #pragma unroll
            for (int f = 0; f < FIN; ++f) gf[f] = fmaf(vh, row[f], gf[f]);
        }
    }

    // ---- writes ----
    if (valid) {
        const int n = b * NW + w;
        out[RES_OFF + n * DD + d] = ov;
        float4* hj = reinterpret_cast<float4*>(out + HJ_OFF + (size_t)(d * NTOT + n) * 16);
        hj[0] = make_float4(gf[0],  gf[1],  gf[2],  gf[3]);
        hj[1] = make_float4(gf[4],  gf[5],  gf[6],  gf[7]);
        hj[2] = make_float4(gf[8],  gf[9],  gf[10], gf[11]);
        hj[3] = make_float4(gf[12], gf[13], gf[14], gf[15]);
    }

    // ---- block reduction of log|g[16]| ----
    float ld = valid ? logf(fabsf(gf[FIN - 1])) : 0.0f;
    __shared__ float red[TILE];
    red[tid] = ld;
    __syncthreads();
    if (tid < 128) red[tid] += red[tid + 128];
    __syncthreads();
    if (tid < 64) {
        float s = red[tid] + red[tid + 64];
        #pragma unroll
        for (int off = 32; off > 0; off >>= 1) s += __shfl_down(s, off);
        if (tid == 0) partials[(b * DD + d) * GX + bx] = s;
    }
}

__global__ void reduce_log(const float* __restrict__ partials, float* __restrict__ out)
{
    const int b = threadIdx.x;   // 64 threads
    float s = 0.0f;
    #pragma unroll
    for (int i = 0; i < DD * GX; ++i) s += partials[b * (DD * GX) + i];
    out[LOG_OFF + b] = s;
}

extern "C" void kernel_launch(void* const* d_in, const int* in_sizes, int n_in,
                              void* d_out, int out_size, void* d_ws, size_t ws_size,
                              hipStream_t stream)
{
    const float* x  = (const float*)d_in[0];
    const float* W0 = (const float*)d_in[1];
    const float* b0 = (const float*)d_in[2];
    const float* a0 = (const float*)d_in[3];
    const float* W1 = (const float*)d_in[4];
    const float* b1 = (const float*)d_in[5];
    const float* a1 = (const float*)d_in[6];
    const float* W2 = (const float*)d_in[7];
    const float* b2 = (const float*)d_in[8];
    const float* a2 = (const float*)d_in[9];
    const float* W3 = (const float*)d_in[10];
    const float* b3 = (const float*)d_in[11];

    float* out      = (float*)d_out;
    float* partials = (float*)d_ws;   // BB*DD*GX = 2048 floats

    dim3 grid(GX, BB, DD);
    fused_mlp<<<grid, TILE, 0, stream>>>(x, W0, b0, a0, W1, b1, a1,
                                         W2, b2, a2, W3, b3, out, partials);
    reduce_log<<<1, BB, 0, stream>>>(partials, out);
}

// Round 3
// 359.206 us; speedup vs baseline: 6.8449x; 6.8449x over previous
//
#include <hip/hip_runtime.h>
#include <cmath>

typedef _Float16 h2 __attribute__((ext_vector_type(2)));

namespace {
constexpr int BB   = 64;
constexpr int TT   = 1002;
constexpr int DD   = 8;
constexpr int HH   = 64;
constexpr int LAGS = 2;
constexpr int NW   = TT - LAGS;        // 1000
constexpr int FIN  = LAGS * DD + 1;    // 17
constexpr int NTOT = BB * NW;          // 64000
constexpr int WPB  = 64;               // windows per block (1 wave)
constexpr int GX   = (NW + WPB - 1) / WPB;   // 16

// output layout (flat, return order)
constexpr int RES_OFF = 0;
constexpr int LOG_OFF = NTOT * DD;
constexpr int HJ_OFF  = LOG_OFF + BB;

// workspace layout, in h2 (4-byte) units
constexpr int OW0F = 0;             constexpr int NW0F = DD * HH * 9;    // fwd L0: pairs along f (17->9, padded)
constexpr int OW0T = OW0F + NW0F;   constexpr int NW0T = DD * FIN * 32;  // bwd L0: pairs along h
constexpr int OW1F = OW0T + NW0T;   constexpr int NWH  = DD * HH * 32;
constexpr int OW1T = OW1F + NWH;
constexpr int OW2F = OW1T + NWH;
constexpr int OW2T = OW2F + NWH;
constexpr int OW3F = OW2T + NWH;    constexpr int NW3F = DD * 32;
constexpr int WTOT = OW3F + NW3F;   // 74752 h2 = ~299 KB
}

__device__ __forceinline__ float fdot2(h2 a, h2 b, float c) {
#if __has_builtin(__builtin_amdgcn_fdot2)
    return __builtin_amdgcn_fdot2(a, b, c, false);
#else
    return c + (float)a[0] * (float)b[0] + (float)a[1] * (float)b[1];
#endif
}

// Convert weights to f16, packed along each GEMV's summation axis,
// plus transposed copies for the backward (VJP) chain.
__global__ void setup_weights(const float* __restrict__ W0, const float* __restrict__ W1,
                              const float* __restrict__ W2, const float* __restrict__ W3,
                              h2* __restrict__ wsp)
{
    for (int i = blockIdx.x * blockDim.x + threadIdx.x; i < WTOT;
         i += gridDim.x * blockDim.x) {
        float a, b;
        if (i < OW0T) {                       // W0F[d][h][k] = (W0[d,h,2k], W0[d,h,2k+1])
            int j = i - OW0F, d = j / (HH * 9), r = j % (HH * 9), h = r / 9, k = r % 9;
            const float* row = W0 + ((size_t)d * HH + h) * FIN;
            a = row[2 * k];
            b = (2 * k + 1 < FIN) ? row[2 * k + 1] : 0.0f;
        } else if (i < OW1F) {                // W0T[d][f][k] = (W0[d,2k,f], W0[d,2k+1,f])
            int j = i - OW0T, d = j / (FIN * 32), r = j % (FIN * 32), f = r / 32, k = r % 32;
            a = W0[((size_t)d * HH + 2 * k) * FIN + f];
            b = W0[((size_t)d * HH + 2 * k + 1) * FIN + f];
        } else if (i < OW1T) {                // W1F[d][g][k] = (W1[d,g,2k], W1[d,g,2k+1])
            int j = i - OW1F, d = j / (HH * 32), r = j % (HH * 32), g = r / 32, k = r % 32;
            const float* row = W1 + ((size_t)d * HH + g) * HH;
            a = row[2 * k]; b = row[2 * k + 1];
        } else if (i < OW2F) {                // W1T[d][h][k] = (W1[d,2k,h], W1[d,2k+1,h])
            int j = i - OW1T, d = j / (HH * 32), r = j % (HH * 32), h = r / 32, k = r % 32;
            a = W1[((size_t)d * HH + 2 * k) * HH + h];
            b = W1[((size_t)d * HH + 2 * k + 1) * HH + h];
        } else if (i < OW2T) {                // W2F
            int j = i - OW2F, d = j / (HH * 32), r = j % (HH * 32), g = r / 32, k = r % 32;
            const float* row = W2 + ((size_t)d * HH + g) * HH;
            a = row[2 * k]; b = row[2 * k + 1];
        } else if (i < OW3F) {                // W2T
            int j = i - OW2T, d = j / (HH * 32), r = j % (HH * 32), h = r / 32, k = r % 32;
            a = W2[((size_t)d * HH + 2 * k) * HH + h];
            b = W2[((size_t)d * HH + 2 * k + 1) * HH + h];
        } else {                              // W3F[d][k] = (W3[d,0,2k], W3[d,0,2k+1])
            int j = i - OW3F, d = j / 32, k = j % 32;
            a = W3[(size_t)d * HH + 2 * k];
            b = W3[(size_t)d * HH + 2 * k + 1];
        }
        h2 p; p[0] = (_Float16)a; p[1] = (_Float16)b;
        wsp[i] = p;
    }
}

// Forward layer: z[g] = b[g] + sum_k dot2(hp[k], WF[g][k]); PReLU; pack pairs
// through column-major LDS (conflict-free, same-lane only) back into hp.
#define FWD_LAYER(WF, bp, Aval, mref)                                       \
  { _Pragma("unroll 1")                                                     \
    for (int g = 0; g < HH; g += 2) {                                       \
      const h2* r0 = (WF) + g * 32;                                         \
      const h2* r1 = r0 + 32;                                               \
      float z0 = (bp)[g], z1 = (bp)[g + 1], y0 = 0.f, y1 = 0.f;             \
      _Pragma("unroll")                                                     \
      for (int k = 0; k < 32; k += 2) {                                     \
        z0 = fdot2(hp[k], r0[k], z0);                                       \
        y0 = fdot2(hp[k + 1], r0[k + 1], y0);                               \
        z1 = fdot2(hp[k], r1[k], z1);                                       \
        y1 = fdot2(hp[k + 1], r1[k + 1], y1);                               \
      }                                                                     \
      z0 += y0; z1 += y1;                                                   \
      const bool p0 = z0 > 0.f, p1 = z1 > 0.f;                              \
      mref |= ((unsigned long long)p0 << g) |                               \
              ((unsigned long long)p1 << (g + 1));                          \
      const float u0 = p0 ? z0 : (Aval) * z0;                               \
      const float u1 = p1 ? z1 : (Aval) * z1;                               \
      h2 pr; pr[0] = (_Float16)u0; pr[1] = (_Float16)u1;                    \
      hbuf[(g >> 1) * WPB + t] = __builtin_bit_cast(unsigned int, pr);      \
    }                                                                       \
    _Pragma("unroll")                                                       \
    for (int k = 0; k < 32; ++k)                                            \
      hp[k] = __builtin_bit_cast(h2, hbuf[k * WPB + t]); }

// Backward layer: vn[h] = (sum_k dot2(vp[k], WT[h][k])) * d_mask[h]
#define BWD_LAYER(WT, Aval, mval)                                           \
  { _Pragma("unroll 1")                                                     \
    for (int hh = 0; hh < HH; hh += 2) {                                    \
      const h2* r0 = (WT) + hh * 32;                                        \
      const h2* r1 = r0 + 32;                                               \
      float z0 = 0.f, z1 = 0.f, y0 = 0.f, y1 = 0.f;                         \
      _Pragma("unroll")                                                     \
      for (int k = 0; k < 32; k += 2) {                                     \
        z0 = fdot2(vp[k], r0[k], z0);                                       \
        y0 = fdot2(vp[k + 1], r0[k + 1], y0);                               \
        z1 = fdot2(vp[k], r1[k], z1);                                       \
        y1 = fdot2(vp[k + 1], r1[k + 1], y1);                               \
      }                                                                     \
      z0 += y0; z1 += y1;                                                   \
      z0 *= (((mval) >> hh) & 1ull) ? 1.0f : (Aval);                        \
      z1 *= (((mval) >> (hh + 1)) & 1ull) ? 1.0f : (Aval);                  \
      h2 pr; pr[0] = (_Float16)z0; pr[1] = (_Float16)z1;                    \
      hbuf[(hh >> 1) * WPB + t] = __builtin_bit_cast(unsigned int, pr);     \
    }                                                                       \
    _Pragma("unroll")                                                       \
    for (int k = 0; k < 32; ++k)                                            \
      vp[k] = __builtin_bit_cast(h2, hbuf[k * WPB + t]); }

__global__ __launch_bounds__(WPB) void fused_mlp(
    const float* __restrict__ x,
    const float* __restrict__ b0, const float* __restrict__ a0,
    const float* __restrict__ b1, const float* __restrict__ a1,
    const float* __restrict__ b2, const float* __restrict__ a2,
    const float* __restrict__ W3, const float* __restrict__ b3,
    const h2* __restrict__ wsp,
    float* __restrict__ out, float* __restrict__ partials)
{
    const int bx = blockIdx.x;     // 0..GX-1
    const int b  = blockIdx.y;     // 0..BB-1
    const int d  = blockIdx.z;     // 0..DD-1
    const int t  = threadIdx.x;    // 0..63 (one wave)
    const int w0 = bx * WPB;

    __shared__ float xs[(WPB + LAGS) * DD];
    __shared__ unsigned int hbuf[32 * WPB];   // [pair][lane], column-major: conflict-free, same-lane

    {
        const int nload = min(WPB + LAGS, TT - w0) * DD;
        const float* src = x + ((size_t)b * TT + w0) * DD;
        for (int i = t; i < nload; i += WPB) xs[i] = src[i];
    }
    __syncthreads();

    const int  w     = w0 + t;
    const bool valid = (w < NW);
    const int  wl    = valid ? t : 0;

    // input: 8 pairs from [x(w),x(w+1)] (contiguous 16 floats) + (x(w+2)[d], 0)
    h2 ip[9];
    #pragma unroll
    for (int k = 0; k < 8; ++k) {
        h2 p; p[0] = (_Float16)xs[wl * DD + 2 * k]; p[1] = (_Float16)xs[wl * DD + 2 * k + 1];
        ip[k] = p;
    }
    { h2 p; p[0] = (_Float16)xs[(wl + LAGS) * DD + d]; p[1] = (_Float16)0.0f; ip[8] = p; }

    const float A0 = a0[d], A1 = a1[d], A2 = a2[d];
    const h2* W0F = wsp + OW0F + (size_t)d * HH * 9;
    const h2* W0T = wsp + OW0T + (size_t)d * FIN * 32;
    const h2* W1F = wsp + OW1F + (size_t)d * HH * 32;
    const h2* W1T = wsp + OW1T + (size_t)d * HH * 32;
    const h2* W2F = wsp + OW2F + (size_t)d * HH * 32;
    const h2* W2T = wsp + OW2T + (size_t)d * HH * 32;
    const h2* W3F = wsp + OW3F + (size_t)d * 32;
    const float* b0p = b0 + d * HH;
    const float* b1p = b1 + d * HH;
    const float* b2p = b2 + d * HH;

    unsigned long long m0 = 0ull, m1 = 0ull, m2 = 0ull;
    h2 hp[32];

    // ---- layer 0 (K=9 pairs) ----
    #pragma unroll 1
    for (int g = 0; g < HH; g += 2) {
        const h2* r0 = W0F + g * 9;
        const h2* r1 = r0 + 9;
        float z0 = b0p[g], z1 = b0p[g + 1];
        #pragma unroll
        for (int k = 0; k < 9; ++k) {
            z0 = fdot2(ip[k], r0[k], z0);
            z1 = fdot2(ip[k], r1[k], z1);
        }
        const bool p0 = z0 > 0.f, p1 = z1 > 0.f;
        m0 |= ((unsigned long long)p0 << g) | ((unsigned long long)p1 << (g + 1));
        const float u0 = p0 ? z0 : A0 * z0;
        const float u1 = p1 ? z1 : A0 * z1;
        h2 pr; pr[0] = (_Float16)u0; pr[1] = (_Float16)u1;
        hbuf[(g >> 1) * WPB + t] = __builtin_bit_cast(unsigned int, pr);
    }
    #pragma unroll
    for (int k = 0; k < 32; ++k) hp[k] = __builtin_bit_cast(h2, hbuf[k * WPB + t]);

    // ---- layers 1,2 ----
    FWD_LAYER(W1F, b1p, A1, m1)
    FWD_LAYER(W2F, b2p, A2, m2)

    // ---- output scalar ----
    float ov;
    {
        float z = b3[d], y = 0.f;
        #pragma unroll
        for (int k = 0; k < 32; k += 2) {
            z = fdot2(hp[k], W3F[k], z);
            y = fdot2(hp[k + 1], W3F[k + 1], y);
        }
        ov = z + y;
    }

    // ---- backward: v2 = W3 * d2 (per-element, from mask bits, f32 math) ----
    h2 vp[32];
    {
        const float* w3p = W3 + (size_t)d * HH;
        #pragma unroll
        for (int k = 0; k < 32; ++k) {
            const float vlo = w3p[2 * k]     * (((m2 >> (2 * k))     & 1ull) ? 1.0f : A2);
            const float vhi = w3p[2 * k + 1] * (((m2 >> (2 * k + 1)) & 1ull) ? 1.0f : A2);
            h2 p; p[0] = (_Float16)vlo; p[1] = (_Float16)vhi;
            vp[k] = p;
        }
    }
    BWD_LAYER(W2T, A1, m1)
    BWD_LAYER(W1T, A0, m0)

    // ---- g[f] = sum_k dot2(vp[k], W0T[f][k]); store hist_jac, log on f=16 ----
    const int n = b * NW + w;
    float ld = 0.0f;
    #pragma unroll 1
    for (int f = 0; f < FIN; ++f) {
        const h2* r = W0T + f * 32;
        float z = 0.f, y = 0.f;
        #pragma unroll
        for (int k = 0; k < 32; k += 2) {
            z = fdot2(vp[k], r[k], z);
            y = fdot2(vp[k + 1], r[k + 1], y);
        }
        const float gv = z + y;
        if (f < FIN - 1) {
            if (valid) out[HJ_OFF + ((size_t)(d * NTOT + n)) * 16 + f] = gv;
        } else {
            ld = valid ? logf(fabsf(gv)) : 0.0f;
        }
    }
    if (valid) out[RES_OFF + (size_t)n * DD + d] = ov;

    // ---- wave reduction of log terms ----
    float s = ld;
    #pragma unroll
    for (int off = 32; off > 0; off >>= 1) s += __shfl_down(s, off);
    if (t == 0) partials[(b * DD + d) * GX + bx] = s;
}

__global__ void reduce_log(const float* __restrict__ partials, float* __restrict__ out)
{
    const int b = threadIdx.x;   // 64 threads
    float s = 0.0f;
    #pragma unroll
    for (int i = 0; i < DD * GX; ++i) s += partials[b * (DD * GX) + i];
    out[LOG_OFF + b] = s;
}

extern "C" void kernel_launch(void* const* d_in, const int* in_sizes, int n_in,
                              void* d_out, int out_size, void* d_ws, size_t ws_size,
                              hipStream_t stream)
{
    const float* x  = (const float*)d_in[0];
    const float* W0 = (const float*)d_in[1];
    const float* b0 = (const float*)d_in[2];
    const float* a0 = (const float*)d_in[3];
    const float* W1 = (const float*)d_in[4];
    const float* b1 = (const float*)d_in[5];
    const float* a1 = (const float*)d_in[6];
    const float* W2 = (const float*)d_in[7];
    const float* b2 = (const float*)d_in[8];
    const float* a2 = (const float*)d_in[9];
    const float* W3 = (const float*)d_in[10];
    const float* b3 = (const float*)d_in[11];

    float* out      = (float*)d_out;
    h2*    wsp      = (h2*)d_ws;
    float* partials = (float*)d_ws + WTOT;   // after weights (h2 is 4 bytes)

    setup_weights<<<64, 256, 0, stream>>>(W0, W1, W2, W3, wsp);

    dim3 grid(GX, BB, DD);
    fused_mlp<<<grid, WPB, 0, stream>>>(x, b0, a0, b1, a1, b2, a2, W3, b3,
                                        wsp, out, partials);
    reduce_log<<<1, BB, 0, stream>>>(partials, out);
}

// Round 4
// 77.266 us; speedup vs baseline: 31.8217x; 4.6489x over previous
//
#include <hip/hip_runtime.h>
#include <cmath>

typedef _Float16 half8 __attribute__((ext_vector_type(8)));
typedef _Float16 half2t __attribute__((ext_vector_type(2)));
typedef float f32x4 __attribute__((ext_vector_type(4)));

namespace {
constexpr int BB   = 64;
constexpr int TT   = 1002;
constexpr int DD   = 8;
constexpr int HH   = 64;
constexpr int LAGS = 2;
constexpr int NW   = TT - LAGS;          // 1000
constexpr int FIN  = LAGS * DD + 1;      // 17
constexpr int NTOT = BB * NW;            // 64000
constexpr int GX   = (NW + 63) / 64;     // 16 (64 windows per wave/block)

// output layout (flat, return order)
constexpr int RES_OFF = 0;
constexpr int LOG_OFF = NTOT * DD;
constexpr int HJ_OFF  = LOG_OFF + BB;

// prepacked A-fragment arrays in d_ws (f16 units).
// A-frag layout per (mt,kc): lane holds A[m][k], m = mt*16 + (lane&15),
// k = kc*32 + (lane>>4)*8 + j, j=0..7  -> [mt][kc][lane][8] contiguous.
constexpr int SZ_A0F = 4 * 1 * 64 * 8;   // fwd L0: A[h][f], K=32 (pad f>=17 -> 0)
constexpr int SZ_AH  = 4 * 2 * 64 * 8;   // 64x64 matrices, K=64
constexpr int SZ_A0T = 2 * 2 * 64 * 8;   // g-step: A[f][h], M=32 (pad f>=17 -> 0)
constexpr int OA0F = 0;
constexpr int OA1F = OA0F + DD * SZ_A0F; // W1 fwd
constexpr int OA2F = OA1F + DD * SZ_AH;  // W2 fwd
constexpr int OA2T = OA2F + DD * SZ_AH;  // W2^T (v1 step)
constexpr int OA1T = OA2T + DD * SZ_AH;  // W1^T (v0 step)
constexpr int OA0T = OA1T + DD * SZ_AH;  // W0^T (g step)
constexpr int WTOT = OA0T + DD * SZ_A0T; // 163840 f16 = 320 KB
}

// Prepack all weights into per-lane MFMA A-fragments (f16).
__global__ void setup_weights(const float* __restrict__ W0, const float* __restrict__ W1,
                              const float* __restrict__ W2, _Float16* __restrict__ wsp)
{
    for (int i = blockIdx.x * blockDim.x + threadIdx.x; i < WTOT;
         i += gridDim.x * blockDim.x) {
        float val;
        if (i < OA1F) {          // A0F: A[m=h][k=f] = W0[d,m,k], K=32 padded
            int j = i - OA0F, d = j / SZ_A0F, r = j % SZ_A0F;
            int mt = r / 512, r2 = r % 512, lane = r2 / 8, jj = r2 % 8;
            int m = mt * 16 + (lane & 15), k = (lane >> 4) * 8 + jj;
            val = (k < FIN) ? W0[((size_t)d * HH + m) * FIN + k] : 0.0f;
        } else if (i < OA2F) {   // A1F: A[m][k] = W1[d,m,k]
            int j = i - OA1F, d = j / SZ_AH, r = j % SZ_AH;
            int mt = r / 1024, r2 = r % 1024, kc = r2 / 512, r3 = r2 % 512;
            int lane = r3 / 8, jj = r3 % 8;
            int m = mt * 16 + (lane & 15), k = kc * 32 + (lane >> 4) * 8 + jj;
            val = W1[((size_t)d * HH + m) * HH + k];
        } else if (i < OA2T) {   // A2F: A[m][k] = W2[d,m,k]
            int j = i - OA2F, d = j / SZ_AH, r = j % SZ_AH;
            int mt = r / 1024, r2 = r % 1024, kc = r2 / 512, r3 = r2 % 512;
            int lane = r3 / 8, jj = r3 % 8;
            int m = mt * 16 + (lane & 15), k = kc * 32 + (lane >> 4) * 8 + jj;
            val = W2[((size_t)d * HH + m) * HH + k];
        } else if (i < OA1T) {   // A2T: A[m=h'][k=g] = W2[d,k,m]
            int j = i - OA2T, d = j / SZ_AH, r = j % SZ_AH;
            int mt = r / 1024, r2 = r % 1024, kc = r2 / 512, r3 = r2 % 512;
            int lane = r3 / 8, jj = r3 % 8;
            int m = mt * 16 + (lane & 15), k = kc * 32 + (lane >> 4) * 8 + jj;
            val = W2[((size_t)d * HH + k) * HH + m];
        } else if (i < OA0T) {   // A1T: A[m=h][k=h'] = W1[d,k,m]
            int j = i - OA1T, d = j / SZ_AH, r = j % SZ_AH;
            int mt = r / 1024, r2 = r % 1024, kc = r2 / 512, r3 = r2 % 512;
            int lane = r3 / 8, jj = r3 % 8;
            int m = mt * 16 + (lane & 15), k = kc * 32 + (lane >> 4) * 8 + jj;
            val = W1[((size_t)d * HH + k) * HH + m];
        } else {                 // A0T: A[m=f][k=h] = W0[d,k,m], M=32 padded
            int j = i - OA0T, d = j / SZ_A0T, r = j % SZ_A0T;
            int mt = r / 1024, r2 = r % 1024, kc = r2 / 512, r3 = r2 % 512;
            int lane = r3 / 8, jj = r3 % 8;
            int m = mt * 16 + (lane & 15), k = kc * 32 + (lane >> 4) * 8 + jj;
            val = (m < FIN) ? W0[((size_t)d * HH + k) * FIN + m] : 0.0f;
        }
        wsp[i] = (_Float16)val;
    }
}

// swizzled LDS byte address for activation tile X[n][k] (rows 128B):
// XOR bits 4-6 with (n&7) -> b128 B-reads and b64 C-writes are ~2-way (free).
__device__ __forceinline__ int swb(int n, int byteoff) {
    return n * 128 + (byteoff ^ ((n & 7) << 4));
}

__global__ __launch_bounds__(64) void fused_mlp(
    const float* __restrict__ x,
    const float* __restrict__ b0, const float* __restrict__ a0,
    const float* __restrict__ b1, const float* __restrict__ a1,
    const float* __restrict__ b2, const float* __restrict__ a2,
    const float* __restrict__ W3, const float* __restrict__ b3,
    const _Float16* __restrict__ wsp,
    float* __restrict__ out, float* __restrict__ partials)
{
    const int bx = blockIdx.x;    // 0..GX-1
    const int b  = blockIdx.y;    // 0..BB-1
    const int d  = blockIdx.z;    // 0..DD-1
    const int t  = threadIdx.x;   // one wave
    const int w0 = bx * 64;

    __shared__ __align__(16) unsigned char Xs[64 * 128];  // X[n][k] f16, swizzled

    // ---- build B0 rows: X[n=t][f] = [x(w,0:8), x(w+1,0:8), x(w+2,d), 0...] ----
    const int w = min(w0 + t, NW - 1);
    {
        const float* xr = x + ((size_t)b * TT + w) * DD;
        f32x4 x0 = *(const f32x4*)(xr + 0);
        f32x4 x1 = *(const f32x4*)(xr + 4);
        f32x4 x2 = *(const f32x4*)(xr + 8);
        f32x4 x3 = *(const f32x4*)(xr + 12);
        float xl = xr[2 * DD + d];
        half8 r0, r1, r2, rz;
        #pragma unroll
        for (int j = 0; j < 4; ++j) {
            r0[j] = (_Float16)x0[j]; r0[4 + j] = (_Float16)x1[j];
            r1[j] = (_Float16)x2[j]; r1[4 + j] = (_Float16)x3[j];
            r2[j] = (_Float16)0.0f;  r2[4 + j] = (_Float16)0.0f;
            rz[j] = (_Float16)0.0f;  rz[4 + j] = (_Float16)0.0f;
        }
        r2[0] = (_Float16)xl;
        *(half8*)&Xs[swb(t, 0)]  = r0;
        *(half8*)&Xs[swb(t, 16)] = r1;
        *(half8*)&Xs[swb(t, 32)] = r2;
        *(half8*)&Xs[swb(t, 48)] = rz;
    }
    __syncthreads();

    const float A0v = a0[d], A1v = a1[d], A2v = a2[d];
    f32x4 C[4][4];   // [mt][nt]: rows h = mt*16+(t>>4)*4+r, col n = nt*16+(t&15)

    // ---- K=64 GEMM into C (B from LDS, A frags from wsp) ----
    auto gemm64 = [&](const _Float16* apk, const float* bp) {
        #pragma unroll
        for (int mt = 0; mt < 4; ++mt) {
            f32x4 bb;
            if (bp) bb = *(const f32x4*)(bp + mt * 16 + (t >> 4) * 4);
            else { bb[0] = 0.f; bb[1] = 0.f; bb[2] = 0.f; bb[3] = 0.f; }
            #pragma unroll
            for (int nt = 0; nt < 4; ++nt) C[mt][nt] = bb;
        }
        half8 Bv[4][2];
        #pragma unroll
        for (int nt = 0; nt < 4; ++nt)
            #pragma unroll
            for (int kc = 0; kc < 2; ++kc)
                Bv[nt][kc] = *(const half8*)&Xs[swb(nt * 16 + (t & 15),
                                                   kc * 64 + (t >> 4) * 16)];
        #pragma unroll
        for (int mt = 0; mt < 4; ++mt) {
            half8 a0f = *(const half8*)(apk + (size_t)((mt * 2 + 0) * 64 + t) * 8);
            half8 a1f = *(const half8*)(apk + (size_t)((mt * 2 + 1) * 64 + t) * 8);
            #pragma unroll
            for (int nt = 0; nt < 4; ++nt) {
                C[mt][nt] = __builtin_amdgcn_mfma_f32_16x16x32_f16(a0f, Bv[nt][0], C[mt][nt], 0, 0, 0);
                C[mt][nt] = __builtin_amdgcn_mfma_f32_16x16x32_f16(a1f, Bv[nt][1], C[mt][nt], 0, 0, 0);
            }
        }
    };

    // ---- store C (as f16) to the LDS activation tile ----
    auto storeC = [&]() {
        #pragma unroll
        for (int mt = 0; mt < 4; ++mt)
            #pragma unroll
            for (int nt = 0; nt < 4; ++nt) {
                half2t lo, hi;
                lo[0] = (_Float16)C[mt][nt][0]; lo[1] = (_Float16)C[mt][nt][1];
                hi[0] = (_Float16)C[mt][nt][2]; hi[1] = (_Float16)C[mt][nt][3];
                uint2 pk;
                pk.x = __builtin_bit_cast(unsigned int, lo);
                pk.y = __builtin_bit_cast(unsigned int, hi);
                *(uint2*)&Xs[swb(nt * 16 + (t & 15), mt * 32 + (t >> 4) * 8)] = pk;
            }
    };

    unsigned long long m0 = 0ull, m1 = 0ull, m2 = 0ull;
    // PReLU in C-fragment space; mask bit = nt*16 + mt*4 + r
    auto prelu = [&](float slope, unsigned long long& mask) {
        #pragma unroll
        for (int mt = 0; mt < 4; ++mt)
            #pragma unroll
            for (int nt = 0; nt < 4; ++nt)
                #pragma unroll
                for (int r = 0; r < 4; ++r) {
                    float z = C[mt][nt][r];
                    bool pos = z > 0.0f;
                    if (pos) mask |= 1ull << (nt * 16 + mt * 4 + r);
                    C[mt][nt][r] = pos ? z : slope * z;
                }
    };
    auto bwd_mask = [&](float slope, unsigned long long mask) {
        #pragma unroll
        for (int mt = 0; mt < 4; ++mt)
            #pragma unroll
            for (int nt = 0; nt < 4; ++nt)
                #pragma unroll
                for (int r = 0; r < 4; ++r)
                    if (!((mask >> (nt * 16 + mt * 4 + r)) & 1ull))
                        C[mt][nt][r] *= slope;
    };

    // ================= forward =================
    // layer 0: K=32 (single k-chunk)
    {
        #pragma unroll
        for (int mt = 0; mt < 4; ++mt) {
            f32x4 bb = *(const f32x4*)(b0 + d * HH + mt * 16 + (t >> 4) * 4);
            #pragma unroll
            for (int nt = 0; nt < 4; ++nt) C[mt][nt] = bb;
        }
        half8 Bv[4];
        #pragma unroll
        for (int nt = 0; nt < 4; ++nt)
            Bv[nt] = *(const half8*)&Xs[swb(nt * 16 + (t & 15), (t >> 4) * 16)];
        const _Float16* apk = wsp + OA0F + (size_t)d * SZ_A0F;
        #pragma unroll
        for (int mt = 0; mt < 4; ++mt) {
            half8 af = *(const half8*)(apk + (size_t)(mt * 64 + t) * 8);
            #pragma unroll
            for (int nt = 0; nt < 4; ++nt)
                C[mt][nt] = __builtin_amdgcn_mfma_f32_16x16x32_f16(af, Bv[nt], C[mt][nt], 0, 0, 0);
        }
    }
    prelu(A0v, m0); storeC(); __syncthreads();

    gemm64(wsp + OA1F + (size_t)d * SZ_AH, b1 + d * HH);
    prelu(A1v, m1); storeC(); __syncthreads();

    gemm64(wsp + OA2F + (size_t)d * SZ_AH, b2 + d * HH);
    prelu(A2v, m2);   // h2 stays in registers (only needed for the output dot)

    // ---- output: out[n] = b3[d] + sum_h h2[h][n] * w3[h] ----
    f32x4 w3v[4];
    #pragma unroll
    for (int mt = 0; mt < 4; ++mt)
        w3v[mt] = *(const f32x4*)(W3 + d * HH + mt * 16 + (t >> 4) * 4);
    float osum[4];
    #pragma unroll
    for (int nt = 0; nt < 4; ++nt) {
        float s = 0.0f;
        #pragma unroll
        for (int mt = 0; mt < 4; ++mt)
            #pragma unroll
            for (int r = 0; r < 4; ++r)
                s = fmaf(w3v[mt][r], C[mt][nt][r], s);
        s += __shfl_xor(s, 16);
        s += __shfl_xor(s, 32);
        osum[nt] = s;
    }
    const float b3v = b3[d];
    if (t < 16) {
        #pragma unroll
        for (int nt = 0; nt < 4; ++nt) {
            int n = w0 + nt * 16 + t;
            if (n < NW)
                out[RES_OFF + ((size_t)b * NW + n) * DD + d] = osum[nt] + b3v;
        }
    }

    // ================= backward =================
    // v2[h][n] = w3[h] * d2(h,n)
    #pragma unroll
    for (int mt = 0; mt < 4; ++mt)
        #pragma unroll
        for (int nt = 0; nt < 4; ++nt)
            #pragma unroll
            for (int r = 0; r < 4; ++r) {
                float dv = ((m2 >> (nt * 16 + mt * 4 + r)) & 1ull) ? 1.0f : A2v;
                C[mt][nt][r] = w3v[mt][r] * dv;
            }
    storeC(); __syncthreads();

    gemm64(wsp + OA2T + (size_t)d * SZ_AH, nullptr);
    bwd_mask(A1v, m1); storeC(); __syncthreads();

    gemm64(wsp + OA1T + (size_t)d * SZ_AH, nullptr);
    bwd_mask(A0v, m0); storeC(); __syncthreads();

    // ---- g = W0^T-frag @ v0 : rows f (2 m-tiles), cols n ----
    f32x4 G[2][4];
    {
        half8 Bv[4][2];
        #pragma unroll
        for (int nt = 0; nt < 4; ++nt)
            #pragma unroll
            for (int kc = 0; kc < 2; ++kc)
                Bv[nt][kc] = *(const half8*)&Xs[swb(nt * 16 + (t & 15),
                                                   kc * 64 + (t >> 4) * 16)];
        const _Float16* apk = wsp + OA0T + (size_t)d * SZ_A0T;
        #pragma unroll
        for (int mt = 0; mt < 2; ++mt) {
            half8 a0f = *(const half8*)(apk + (size_t)((mt * 2 + 0) * 64 + t) * 8);
            half8 a1f = *(const half8*)(apk + (size_t)((mt * 2 + 1) * 64 + t) * 8);
            #pragma unroll
            for (int nt = 0; nt < 4; ++nt) {
                f32x4 z; z[0] = 0.f; z[1] = 0.f; z[2] = 0.f; z[3] = 0.f;
                z = __builtin_amdgcn_mfma_f32_16x16x32_f16(a0f, Bv[nt][0], z, 0, 0, 0);
                z = __builtin_amdgcn_mfma_f32_16x16x32_f16(a1f, Bv[nt][1], z, 0, 0, 0);
                G[mt][nt] = z;
            }
        }
    }

    // hist_jac: f = (t>>4)*4 + r (mt=0 covers f 0..15), n = nt*16 + (t&15)
    #pragma unroll
    for (int nt = 0; nt < 4; ++nt) {
        int n = w0 + nt * 16 + (t & 15);
        if (n < NW)
            *(f32x4*)(out + HJ_OFF + ((size_t)d * NTOT + (size_t)b * NW + n) * 16
                      + (t >> 4) * 4) = G[0][nt];
    }

    // log|g[16]|: row f=16 lives in G[1][nt][0] on lanes 0..15
    float ld = 0.0f;
    if ((t >> 4) == 0) {
        #pragma unroll
        for (int nt = 0; nt < 4; ++nt) {
            int n = w0 + nt * 16 + t;
            if (n < NW) ld += logf(fabsf(G[1][nt][0]));
        }
    }
    #pragma unroll
    for (int off = 32; off > 0; off >>= 1) ld += __shfl_down(ld, off);
    if (t == 0) partials[(b * DD + d) * GX + bx] = ld;
}

__global__ void reduce_log(const float* __restrict__ partials, float* __restrict__ out)
{
    const int b = threadIdx.x;   // 64 threads
    float s = 0.0f;
    #pragma unroll
    for (int i = 0; i < DD * GX; ++i) s += partials[b * (DD * GX) + i];
    out[LOG_OFF + b] = s;
}

extern "C" void kernel_launch(void* const* d_in, const int* in_sizes, int n_in,
                              void* d_out, int out_size, void* d_ws, size_t ws_size,
                              hipStream_t stream)
{
    const float* x  = (const float*)d_in[0];
    const float* W0 = (const float*)d_in[1];
    const float* b0 = (const float*)d_in[2];
    const float* a0 = (const float*)d_in[3];
    const float* W1 = (const float*)d_in[4];
    const float* b1 = (const float*)d_in[5];
    const float* a1 = (const float*)d_in[6];
    const float* W2 = (const float*)d_in[7];
    const float* b2 = (const float*)d_in[8];
    const float* a2 = (const float*)d_in[9];
    const float* W3 = (const float*)d_in[10];
    const float* b3 = (const float*)d_in[11];

    float*     out      = (float*)d_out;
    _Float16*  wsp      = (_Float16*)d_ws;
    float*     partials = (float*)((char*)d_ws + (size_t)WTOT * 2);  // 8192 floats

    setup_weights<<<160, 1024, 0, stream>>>(W0, W1, W2, wsp);

    dim3 grid(GX, BB, DD);
    fused_mlp<<<grid, 64, 0, stream>>>(x, b0, a0, b1, a1, b2, a2, W3, b3,
                                       wsp, out, partials);
    reduce_log<<<1, BB, 0, stream>>>(partials, out);
}